// Round 1
// baseline (99.288 us; speedup 1.0000x reference)
//
#include <hip/hip_runtime.h>
#include <stdint.h>

#define GXD 512
#define GYD 512
#define GZD 1
#define NCELL (GXD*GYD*GZD)      // 262144
#define SENTINEL NCELL
#define NB 4
#define NPTS 200000
#define MAXVOX 20000
#define MAXPTS 30

// ---------------- init: coors default rows (b, -1, -1, -1) ----------------
__global__ void init_coors_kernel(float* __restrict__ out_coors) {
    int r = blockIdx.x * blockDim.x + threadIdx.x;
    if (r >= NB * MAXVOX) return;
    int b = r / MAXVOX;
    float4 v = make_float4((float)b, -1.0f, -1.0f, -1.0f);
    reinterpret_cast<float4*>(out_coors)[r] = v;
}

// ---------------- pass 1: bin points, count per cell ----------------
__global__ void bin_kernel(const float* __restrict__ pts,
                           int* __restrict__ lin_buf,
                           int* __restrict__ counts) {
    int g = blockIdx.x * blockDim.x + threadIdx.x;
    if (g >= NB * NPTS) return;
    float4 p = reinterpret_cast<const float4*>(pts)[g];
    // exact replication of reference f32 math: (x - pc_min) / voxel, floor, int cast
    float fx = floorf((p.x - (-51.2f)) / 0.2f);
    float fy = floorf((p.y - (-51.2f)) / 0.2f);
    float fz = floorf((p.z - (-5.0f)) / 8.0f);
    int cx = (int)fx, cy = (int)fy, cz = (int)fz;
    int lin = SENTINEL;
    if (cx >= 0 && cx < GXD && cy >= 0 && cy < GYD && cz >= 0 && cz < GZD)
        lin = (cz * GYD + cy) * GXD + cx;
    lin_buf[g] = lin;
    if (lin < SENTINEL) {
        int b = g / NPTS;
        atomicAdd(&counts[b * NCELL + lin], 1);
    }
}

// ---------------- pass 2a: per-block packed exclusive scan ----------------
// value per cell: low32 = count, high32 = (count>0)
__global__ void scan1_kernel(const int* __restrict__ counts,
                             unsigned long long* __restrict__ scanbuf,
                             unsigned long long* __restrict__ bsums) {
    int b = blockIdx.y;
    int blk = blockIdx.x;      // 0..255, each block covers 1024 cells
    int tid = threadIdx.x;     // 0..255, each thread covers 4 consecutive cells
    const int4* c4 = reinterpret_cast<const int4*>(counts + (size_t)b * NCELL + blk * 1024);
    int4 c = c4[tid];
    unsigned long long v0 = (unsigned int)c.x | ((unsigned long long)(c.x > 0) << 32);
    unsigned long long v1 = (unsigned int)c.y | ((unsigned long long)(c.y > 0) << 32);
    unsigned long long v2 = (unsigned int)c.z | ((unsigned long long)(c.z > 0) << 32);
    unsigned long long v3 = (unsigned int)c.w | ((unsigned long long)(c.w > 0) << 32);
    unsigned long long i0 = v0, i1 = i0 + v1, i2 = i1 + v2, i3 = i2 + v3;

    __shared__ unsigned long long s[256];
    s[tid] = i3;
    __syncthreads();
    for (int off = 1; off < 256; off <<= 1) {
        unsigned long long a = (tid >= off) ? s[tid - off] : 0ull;
        __syncthreads();
        s[tid] += a;
        __syncthreads();
    }
    unsigned long long texcl = s[tid] - i3;   // exclusive prefix of this thread within block

    unsigned long long* so = scanbuf + (size_t)b * NCELL + blk * 1024 + tid * 4;
    so[0] = texcl;
    so[1] = texcl + i0;
    so[2] = texcl + i1;
    so[3] = texcl + i2;
    if (tid == 255) bsums[b * 256 + blk] = s[255];
}

// ---------------- pass 2b: exclusive scan of block sums (per batch) ----------------
__global__ void scan2_kernel(unsigned long long* __restrict__ bsums) {
    int b = blockIdx.x;
    int tid = threadIdx.x;   // 256 threads
    __shared__ unsigned long long s[256];
    unsigned long long v = bsums[b * 256 + tid];
    s[tid] = v;
    __syncthreads();
    for (int off = 1; off < 256; off <<= 1) {
        unsigned long long a = (tid >= off) ? s[tid - off] : 0ull;
        __syncthreads();
        s[tid] += a;
        __syncthreads();
    }
    bsums[b * 256 + tid] = s[tid] - v;   // exclusive
}

// ---------------- pass 3: scatter point indices into per-cell segments ----------------
__global__ void scatter_kernel(const int* __restrict__ lin_buf,
                               const unsigned long long* __restrict__ scanbuf,
                               const unsigned long long* __restrict__ bsums,
                               int* __restrict__ cursor,
                               int* __restrict__ order_buf) {
    int g = blockIdx.x * blockDim.x + threadIdx.x;
    if (g >= NB * NPTS) return;
    int lin = lin_buf[g];
    if (lin >= SENTINEL) return;
    int b = g / NPTS;
    int i = g - b * NPTS;
    unsigned long long ex = scanbuf[(size_t)b * NCELL + lin] + bsums[b * 256 + (lin >> 10)];
    int start = (int)(ex & 0xffffffffull);
    int slot = atomicAdd(&cursor[b * NCELL + lin], 1);
    order_buf[(size_t)b * NPTS + start + slot] = i;
}

// ---------------- pass 4: finalize each occupied cell ----------------
__global__ void finalize_kernel(const int* __restrict__ counts,
                                const unsigned long long* __restrict__ scanbuf,
                                const unsigned long long* __restrict__ bsums,
                                const int* __restrict__ order_buf,
                                const float* __restrict__ pts,
                                float* __restrict__ out_vox,
                                float* __restrict__ out_coors,
                                float* __restrict__ out_cnt) {
    int g = blockIdx.x * blockDim.x + threadIdx.x;
    if (g >= NB * NCELL) return;
    int b = g / NCELL;
    int cell = g - b * NCELL;
    int cnt = counts[g];
    if (cnt == 0) return;
    unsigned long long ex = scanbuf[g] + bsums[b * 256 + (cell >> 10)];
    int gid = (int)(ex >> 32);
    if (gid >= MAXVOX) return;
    int start = (int)(ex & 0xffffffffull);
    const int* seg = order_buf + (size_t)b * NPTS + start;
    int kept = cnt < MAXPTS ? cnt : MAXPTS;
    int row = b * MAXVOX + gid;
    float* vox = out_vox + (size_t)row * (MAXPTS * 4);

    // deterministic order: repeatedly select smallest original index
    int last = -1;
    for (int k = 0; k < kept; ++k) {
        int best = 0x7fffffff;
        for (int j = 0; j < cnt; ++j) {
            int v = seg[j];
            if (v > last && v < best) best = v;
        }
        last = best;
        float4 p = reinterpret_cast<const float4*>(pts)[(size_t)b * NPTS + best];
        reinterpret_cast<float4*>(vox)[k] = p;
    }

    int cx = cell & (GXD - 1);
    int cy = (cell >> 9) & (GYD - 1);
    int cz = cell >> 18;
    float4 co = make_float4((float)b, (float)cz, (float)cy, (float)cx);
    reinterpret_cast<float4*>(out_coors)[row] = co;
    out_cnt[row] = (float)kept;
}

extern "C" void kernel_launch(void* const* d_in, const int* in_sizes, int n_in,
                              void* d_out, int out_size, void* d_ws, size_t ws_size,
                              hipStream_t stream) {
    (void)in_sizes; (void)n_in; (void)ws_size;
    const float* pts = (const float*)d_in[0];
    float* out = (float*)d_out;

    float* out_vox   = out;                                             // 4*20000*30*4 = 9,600,000 f32
    float* out_coors = out + (size_t)NB * MAXVOX * MAXPTS * 4;          // 4*20000*4   =   320,000 f32
    float* out_cnt   = out_coors + (size_t)NB * MAXVOX * 4;             // 4*20000     =    80,000 f32

    // workspace layout
    char* w = (char*)d_ws;
    int* lin_buf = (int*)w;                         w += (size_t)NB * NPTS * 4;     // 3.2 MB
    int* counts  = (int*)w;                         w += (size_t)NB * NCELL * 4;    // 4 MB
    int* cursor  = (int*)w;                         w += (size_t)NB * NCELL * 4;    // 4 MB
    int* order_buf = (int*)w;                       w += (size_t)NB * NPTS * 4;     // 3.2 MB
    unsigned long long* scanbuf = (unsigned long long*)w; w += (size_t)NB * NCELL * 8; // 8 MB
    unsigned long long* bsums   = (unsigned long long*)w; w += (size_t)NB * 256 * 8;

    // zero output (voxel features + counts default 0) and counters
    hipMemsetAsync(d_out, 0, (size_t)out_size * 4, stream);
    hipMemsetAsync(counts, 0, (size_t)NB * NCELL * 4 * 2, stream);   // counts + cursor (contiguous)

    init_coors_kernel<<<(NB * MAXVOX + 255) / 256, 256, 0, stream>>>(out_coors);
    bin_kernel<<<(NB * NPTS + 255) / 256, 256, 0, stream>>>(pts, lin_buf, counts);
    scan1_kernel<<<dim3(256, NB), 256, 0, stream>>>(counts, scanbuf, bsums);
    scan2_kernel<<<NB, 256, 0, stream>>>(bsums);
    scatter_kernel<<<(NB * NPTS + 255) / 256, 256, 0, stream>>>(lin_buf, scanbuf, bsums, cursor, order_buf);
    finalize_kernel<<<(NB * NCELL + 255) / 256, 256, 0, stream>>>(counts, scanbuf, bsums, order_buf, pts,
                                                                  out_vox, out_coors, out_cnt);
}